// Round 6
// baseline (1628.525 us; speedup 1.0000x reference)
//
#include <hip/hip_runtime.h>
#include <hip/hip_bf16.h>

#define NB 2
#define L 256
#define H 8
#define D 64
#define E 512
#define NL (NB * L)
#define RSQRT2 0.70710678118654752f

// MEASUREMENT ROUND: differential grid replication. Each kernel's grid is
// multiplied by a rep factor; replicas recompute bitwise-identical values
// (deterministic, no atomics -> benign write races, output unchanged).
// Purpose: (a) per-kernel T = top5_row_dur / reps, (b) each kernel's own
// hbm_gbps / VALUBusy / occupancy counters become visible in top-5.
// Reps: k1 x16, k2pre x16, k2f x8, k3 x16, k0 x1.

// ---------------- K0: transpose Wout [E][E] -> WoutT [c][e] ----------------
__global__ __launch_bounds__(256) void k0_transpose(const float* __restrict__ Wout,
                                                    float* __restrict__ WoutT) {
    __shared__ float tile[64][65];
    int t = threadIdx.x;
    int bi = blockIdx.x >> 3;   // e-tile
    int bj = blockIdx.x & 7;    // c-tile
    int tx = t & 63, ty = t >> 6;  // ty 0..3
#pragma unroll
    for (int m = 0; m < 16; m++) {
        int el = ty + (m << 2);
        tile[el][tx] = Wout[(size_t)(bi * 64 + el) * E + bj * 64 + tx];
    }
    __syncthreads();
#pragma unroll
    for (int m = 0; m < 16; m++) {
        int cl = ty + (m << 2);
        WoutT[(size_t)(bj * 64 + cl) * E + bi * 64 + tx] = tile[tx][cl];
    }
}

// ---------------- K1: per-(n,l) projections ----------------
__device__ __forceinline__ float dot64(const float* __restrict__ a,
                                       const float* __restrict__ w) {
    const float4* a4 = (const float4*)a;
    const float4* w4 = (const float4*)w;
    float acc = 0.f;
#pragma unroll
    for (int j = 0; j < 16; j++) {
        float4 x = a4[j], y = w4[j];
        acc = fmaf(x.x, y.x, acc);
        acc = fmaf(x.y, y.y, acc);
        acc = fmaf(x.z, y.z, acc);
        acc = fmaf(x.w, y.w, acc);
    }
    return acc;
}

__global__ __launch_bounds__(256) void k1_proj(
    const float* __restrict__ values, const float* __restrict__ keys,
    const float* __restrict__ query, const float* __restrict__ pos,
    const float* __restrict__ Wv, const float* __restrict__ Wk,
    const float* __restrict__ Wq, const float* __restrict__ Wpq,
    const float* __restrict__ Wpk, const float* __restrict__ Wrk,
    const float* __restrict__ Wrq,
    float* __restrict__ qv_ws, float* __restrict__ kv_ws,
    float* __restrict__ vv_ws, float* __restrict__ pq_ws,
    float* __restrict__ pk_ws, float* __restrict__ qrk_ws,
    float* __restrict__ krq_ws) {
    __shared__ float xq[E], xk[E], xv[E], xp[E];
    __shared__ float qs[E], ks[E];
    int t = threadIdx.x;
    int nl = blockIdx.x & 511;  // x16 replication
    size_t base = (size_t)nl * E;
    for (int j = t; j < E; j += 256) {
        xq[j] = query[base + j];
        xk[j] = keys[base + j];
        xv[j] = values[base + j];
        xp[j] = pos[base + j];
    }
    __syncthreads();
#pragma unroll
    for (int cc = 0; cc < 2; cc++) {
        int c = t + cc * 256;
        int h = c >> 6, i = c & 63;
        const float* xqh = xq + (h << 6);
        const float* xkh = xk + (h << 6);
        const float* xvh = xv + (h << 6);
        const float* xph = xp + (h << 6);
        float q_c = dot64(xqh, Wq + (i << 6));
        float k_c = dot64(xkh, Wk + (i << 6));
        float v_c = dot64(xvh, Wv + (i << 6));
        float pq_c = dot64(xph, Wpq + (i << 6));
        float pk_c = dot64(xph, Wpk + (i << 6));
        qv_ws[base + c] = q_c;
        kv_ws[base + c] = k_c;
        vv_ws[base + c] = v_c;
        pq_ws[base + c] = pq_c;
        pk_ws[base + c] = pk_c;
        qs[c] = q_c;
        ks[c] = k_c;
    }
    __syncthreads();
#pragma unroll
    for (int cc = 0; cc < 2; cc++) {
        int c = t + cc * 256;
        int h = c >> 6, d = c & 63;
        float aq = 0.f, ak = 0.f;
        const float* qh = qs + (h << 6);
        const float* kh = ks + (h << 6);
#pragma unroll 8
        for (int i = 0; i < 64; i++) {
            aq = fmaf(qh[i], Wrk[(i << 6) + d], aq);
            ak = fmaf(kh[i], Wrq[(i << 6) + d], ak);
        }
        qrk_ws[base + c] = aq;
        krq_ws[base + c] = ak;
    }
}

// ---------------- K2pre: e_ws = (q.k + pq.pk)*rsqrt2 + mask ----------------
__global__ __launch_bounds__(256) void k2pre(
    const float* __restrict__ qv_ws, const float* __restrict__ kv_ws,
    const float* __restrict__ pq_ws, const float* __restrict__ pk_ws,
    const float* __restrict__ mask, float* __restrict__ e_ws) {
    __shared__ float qs[8 * 64], ps[8 * 64];
    int t = threadIdx.x;
    int b = blockIdx.x & 511;  // x16 replication
    int qt = b & 31;
    int h = (b >> 5) & 7;
    int n = b >> 8;
    int nb = n << 8;
    int q0 = qt << 3;
    int k = t;
#pragma unroll
    for (int it = 0; it < 2; it++) {
        int idx = t + (it << 8);
        int q = idx >> 6, d = idx & 63;
        size_t g = (size_t)(nb + q0 + q) * E + (h << 6) + d;
        qs[idx] = qv_ws[g];
        ps[idx] = pq_ws[g];
    }
    __syncthreads();
    const float4* kv4p = (const float4*)(kv_ws + (size_t)(nb + k) * E + (h << 6));
    const float4* pk4p = (const float4*)(pk_ws + (size_t)(nb + k) * E + (h << 6));
    float acc[8];
#pragma unroll
    for (int q = 0; q < 8; q++) acc[q] = 0.f;
#pragma unroll
    for (int d4 = 0; d4 < 16; d4++) {
        float4 kv4 = kv4p[d4];
        float4 pk4 = pk4p[d4];
#pragma unroll
        for (int q = 0; q < 8; q++) {
            float4 q4 = ((const float4*)qs)[(q << 4) + d4];
            float4 p4 = ((const float4*)ps)[(q << 4) + d4];
            float a = acc[q];
            a = fmaf(q4.x, kv4.x, a);
            a = fmaf(q4.y, kv4.y, a);
            a = fmaf(q4.z, kv4.z, a);
            a = fmaf(q4.w, kv4.w, a);
            a = fmaf(p4.x, pk4.x, a);
            a = fmaf(p4.y, pk4.y, a);
            a = fmaf(p4.z, pk4.z, a);
            a = fmaf(p4.w, pk4.w, a);
            acc[q] = a;
        }
    }
    float mk = (1.0f - mask[nb + k]) * (-1e9f);
#pragma unroll
    for (int q = 0; q < 8; q++) {
        e_ws[(size_t)(nb + q0 + q) * (H * L) + (h << 8) + k] = acc[q] * RSQRT2 + mk;
    }
}

// ---------------- K2f: fused rel-energy + softmax + attn@V ----------------
#define K2F_LOAD(RR, RK, b_)                                              \
    do {                                                                  \
        _Pragma("unroll") for (int jj = 0; jj < 8; jj++) {                \
            int k_ = ((b_) << 4) + (jj << 1) + rowsel;                    \
            RR[jj] = *(const float4*)(relb + ((size_t)k_ << 9) + cq);     \
            RK[jj] = *(const float4*)(krqb + ((size_t)k_ << 9) + cq);     \
        }                                                                 \
    } while (0)

#define K2F_COMP(RR, RK, b_)                                              \
    do {                                                                  \
        _Pragma("unroll") for (int jj = 0; jj < 8; jj++) {                \
            float wx = qrk4.x + RK[jj].x;                                 \
            float wy = qrk4.y + RK[jj].y;                                 \
            float wz = qrk4.z + RK[jj].z;                                 \
            float ww = qrk4.w + RK[jj].w;                                 \
            float p = RR[jj].x * wx;                                      \
            p = fmaf(RR[jj].y, wy, p);                                    \
            p = fmaf(RR[jj].z, wz, p);                                    \
            p = fmaf(RR[jj].w, ww, p);                                    \
            p += __shfl_down(p, 8, 16);                                   \
            p += __shfl_down(p, 4, 16);                                   \
            p += __shfl_down(p, 2, 16);                                   \
            p += __shfl_down(p, 1, 16);                                   \
            if (sub == 0) {                                               \
                int k_ = ((b_) << 4) + (jj << 1) + rowsel;                \
                r_s[(h << 8) + k_] = p * RSQRT2;                          \
            }                                                             \
        }                                                                 \
    } while (0)

__global__ __launch_bounds__(256, 2) void k2f(
    const float* __restrict__ rel, const float* __restrict__ qrk_ws,
    const float* __restrict__ krq_ws, const float* __restrict__ e_ws,
    const float* __restrict__ vv_ws, float* __restrict__ attn_ws) {
    __shared__ float e_s[H * L];
    __shared__ float r_s[H * L];
    __shared__ float PS[2 * E];
    __shared__ float inv_s[H];
    int t = threadIdx.x;
    int nq = blockIdx.x & 511;  // x8 replication
    int n = nq >> 8;

    {
        const float4* src = (const float4*)(e_ws + (size_t)nq * (H * L));
        ((float4*)e_s)[t] = src[t];
        ((float4*)e_s)[t + 256] = src[t + 256];
    }

    int lane128 = t & 127;
    int rowsel = t >> 7;
    int cq = lane128 << 2;
    int h = lane128 >> 4;
    int sub = t & 15;

    const float* relb = rel + (((size_t)nq) << 8) * E;
    const float* krqb = krq_ws + (((size_t)(n << 8))) * E;
    float4 qrk4 = *(const float4*)(qrk_ws + (size_t)nq * E + cq);

    float4 rAr[8], rAk[8], rBr[8], rBk[8];
    K2F_LOAD(rAr, rAk, 0);
#pragma unroll
    for (int b = 0; b < 16; b += 2) {
        K2F_LOAD(rBr, rBk, b + 1);
        K2F_COMP(rAr, rAk, b);
        if (b + 2 < 16) K2F_LOAD(rAr, rAk, b + 2);
        K2F_COMP(rBr, rBk, b + 1);
    }
    __syncthreads();

    {
        int hh = t >> 5;
        int l32 = t & 31;
        float* eh = e_s + (hh << 8);
        const float* rh = r_s + (hh << 8);
        float x[8];
        float m = -INFINITY;
#pragma unroll
        for (int j = 0; j < 8; j++) {
            int idx = l32 + (j << 5);
            x[j] = eh[idx] + rh[idx];
            m = fmaxf(m, x[j]);
        }
#pragma unroll
        for (int off = 16; off > 0; off >>= 1) m = fmaxf(m, __shfl_xor(m, off, 32));
        float s = 0.f;
#pragma unroll
        for (int j = 0; j < 8; j++) {
            int idx = l32 + (j << 5);
            float ev = __expf(x[j] - m);
            eh[idx] = ev;
            s += ev;
        }
#pragma unroll
        for (int off = 16; off > 0; off >>= 1) s += __shfl_xor(s, off, 32);
        if (l32 == 0) inv_s[hh] = 1.0f / s;
    }
    __syncthreads();

    {
        int c4 = (t & 127) << 2;
        int kseg = t >> 7;
        int h1 = c4 >> 6;
        const float* eh = e_s + (h1 << 8) + (kseg << 7);
        const float* vb = vv_ws + ((size_t)((n << 8) + (kseg << 7))) * E + c4;
        float4 acc = {0.f, 0.f, 0.f, 0.f};
#pragma unroll 16
        for (int k = 0; k < 128; k++) {
            float ev = eh[k];
            float4 v4 = *(const float4*)(vb + ((size_t)k << 9));
            acc.x = fmaf(ev, v4.x, acc.x);
            acc.y = fmaf(ev, v4.y, acc.y);
            acc.z = fmaf(ev, v4.z, acc.z);
            acc.w = fmaf(ev, v4.w, acc.w);
        }
        *(float4*)(PS + kseg * E + c4) = acc;
    }
    __syncthreads();

    {
        float v0 = PS[t] + PS[E + t];
        attn_ws[(size_t)nq * E + t] = v0 * inv_s[t >> 6];
        float v1 = PS[256 + t] + PS[E + 256 + t];
        attn_ws[(size_t)nq * E + 256 + t] = v1 * inv_s[(256 + t) >> 6];
    }
}

// ---------------- K3: out = attn @ Wout.T + bout (4 rows / block) ----------------
__global__ __launch_bounds__(512) void k3_out(const float* __restrict__ attn_ws,
                                              const float* __restrict__ WoutT,
                                              const float* __restrict__ bout,
                                              float* __restrict__ out) {
    __shared__ float As[4 * E];
    int t = threadIdx.x;
    int r0 = (blockIdx.x & 127) << 2;  // x16 replication
    for (int j = t; j < 4 * E; j += 512) As[j] = attn_ws[(size_t)r0 * E + j];
    __syncthreads();
    float b0 = bout[t];
    float a0 = b0, a1 = b0, a2 = b0, a3 = b0;
#pragma unroll 8
    for (int c = 0; c < E; c++) {
        float w = WoutT[((size_t)c << 9) + t];
        a0 = fmaf(As[c], w, a0);
        a1 = fmaf(As[E + c], w, a1);
        a2 = fmaf(As[2 * E + c], w, a2);
        a3 = fmaf(As[3 * E + c], w, a3);
    }
    out[(size_t)(r0 + 0) * E + t] = a0;
    out[(size_t)(r0 + 1) * E + t] = a1;
    out[(size_t)(r0 + 2) * E + t] = a2;
    out[(size_t)(r0 + 3) * E + t] = a3;
}

extern "C" void kernel_launch(void* const* d_in, const int* in_sizes, int n_in,
                              void* d_out, int out_size, void* d_ws, size_t ws_size,
                              hipStream_t stream) {
    const float* values = (const float*)d_in[0];
    const float* keys = (const float*)d_in[1];
    const float* query = (const float*)d_in[2];
    const float* pos = (const float*)d_in[3];
    const float* rel = (const float*)d_in[4];
    const float* mask = (const float*)d_in[5];
    const float* Wv = (const float*)d_in[6];
    const float* Wk = (const float*)d_in[7];
    const float* Wq = (const float*)d_in[8];
    const float* Wpq = (const float*)d_in[9];
    const float* Wpk = (const float*)d_in[10];
    const float* Wrk = (const float*)d_in[11];
    const float* Wrq = (const float*)d_in[12];
    const float* Wout = (const float*)d_in[13];
    const float* bout = (const float*)d_in[14];
    float* out = (float*)d_out;

    float* ws = (float*)d_ws;
    const size_t SZ = (size_t)NL * E;  // 262144 floats = 1 MB
    float* qv_ws = ws + 0 * SZ;
    float* kv_ws = ws + 1 * SZ;
    float* vv_ws = ws + 2 * SZ;
    float* pq_ws = ws + 3 * SZ;
    float* pk_ws = ws + 4 * SZ;
    float* qrk_ws = ws + 5 * SZ;
    float* krq_ws = ws + 6 * SZ;
    float* attn_ws = ws + 7 * SZ;
    float* WoutT = ws + 8 * SZ;
    float* e_ws = ws + 9 * SZ;  // NL * H * L floats = 4 MB

    // Differential replication: per-kernel dur = top5_row / reps.
    k0_transpose<<<64, 256, 0, stream>>>(Wout, WoutT);
    k1_proj<<<512 * 16, 256, 0, stream>>>(values, keys, query, pos, Wv, Wk, Wq,
                                          Wpq, Wpk, Wrk, Wrq, qv_ws, kv_ws,
                                          vv_ws, pq_ws, pk_ws, qrk_ws, krq_ws);
    k2pre<<<512 * 16, 256, 0, stream>>>(qv_ws, kv_ws, pq_ws, pk_ws, mask, e_ws);
    k2f<<<512 * 8, 256, 0, stream>>>(rel, qrk_ws, krq_ws, e_ws, vv_ws, attn_ws);
    k3_out<<<128 * 16, 512, 0, stream>>>(attn_ws, WoutT, bout, out);
}

// Round 7
// 533.462 us; speedup vs baseline: 3.0527x; 3.0527x over previous
//
#include <hip/hip_runtime.h>
#include <hip/hip_bf16.h>

#define NB 2
#define L 256
#define H 8
#define D 64
#define E 512
#define NL (NB * L)
#define RSQRT2 0.70710678118654752f

// ---------------- K0: transpose Wout [E][E] -> WoutT [c][e], plus the five
// 64x64 head weights (Wq,Wk,Wv,Wpq,Wpk) -> WT[j][i] copies for k1's
// fully-coalesced reads. Grid = 64 Wout tiles + 5 small matrices.
__global__ __launch_bounds__(256) void k0_transpose(
    const float* __restrict__ Wout, float* __restrict__ WoutT,
    const float* __restrict__ Wq, const float* __restrict__ Wk,
    const float* __restrict__ Wv, const float* __restrict__ Wpq,
    const float* __restrict__ Wpk,
    float* __restrict__ WqT, float* __restrict__ WkT, float* __restrict__ WvT,
    float* __restrict__ WpqT, float* __restrict__ WpkT) {
    __shared__ float tile[64][65];
    int t = threadIdx.x;
    int tx = t & 63, ty = t >> 6;  // ty 0..3
    if (blockIdx.x < 64) {
        int bi = blockIdx.x >> 3;   // e-tile
        int bj = blockIdx.x & 7;    // c-tile
#pragma unroll
        for (int m = 0; m < 16; m++) {
            int el = ty + (m << 2);
            tile[el][tx] = Wout[(size_t)(bi * 64 + el) * E + bj * 64 + tx];
        }
        __syncthreads();
#pragma unroll
        for (int m = 0; m < 16; m++) {
            int cl = ty + (m << 2);
            WoutT[(size_t)(bj * 64 + cl) * E + bi * 64 + tx] = tile[tx][cl];
        }
    } else {
        const float* src;
        float* dst;
        switch (blockIdx.x - 64) {
            case 0: src = Wq;  dst = WqT;  break;
            case 1: src = Wk;  dst = WkT;  break;
            case 2: src = Wv;  dst = WvT;  break;
            case 3: src = Wpq; dst = WpqT; break;
            default: src = Wpk; dst = WpkT; break;
        }
#pragma unroll
        for (int m = 0; m < 16; m++) {
            int r = ty + (m << 2);
            tile[r][tx] = src[(r << 6) + tx];
        }
        __syncthreads();
#pragma unroll
        for (int m = 0; m < 16; m++) {
            int r = ty + (m << 2);
            dst[(r << 6) + tx] = tile[tx][r];  // WT[r][c] = W[c][r]
        }
    }
}

// ---------------- K1 v4: per-token projections, all loads coalesced ----------
// grid: NL/2 = 256 blocks x 256 threads. Block = 2 tokens. Thread owns 4
// consecutive channels of one token. Weight reads: WT[j][4li..4li+3] float4 =
// 256B contiguous per 16-lane group, identical across head-groups (wave-wide
// broadcast). x reads: LDS rows padded to stride 68 -> conflict-free.
#define XS 68  // padded row stride (floats) per (array, token, head)

__global__ __launch_bounds__(256) void k1_proj(
    const float* __restrict__ values, const float* __restrict__ keys,
    const float* __restrict__ query, const float* __restrict__ pos,
    const float* __restrict__ WqT, const float* __restrict__ WkT,
    const float* __restrict__ WvT, const float* __restrict__ WpqT,
    const float* __restrict__ WpkT, const float* __restrict__ Wrk,
    const float* __restrict__ Wrq,
    float* __restrict__ qv_ws, float* __restrict__ kv_ws,
    float* __restrict__ vv_ws, float* __restrict__ pq_ws,
    float* __restrict__ pk_ws, float* __restrict__ qrk_ws,
    float* __restrict__ krq_ws) {
    __shared__ float x_lds[4][2][8 * XS];   // [array][token][head*XS + j]
    __shared__ float qk_lds[2][2][8 * XS];  // [q/k][token][head*XS + i]
    int t = threadIdx.x;
    int tok0 = blockIdx.x << 1;

    // ---- stage inputs: thread t handles float4 #t of each array (2 tok x 128)
    {
        int tk = t >> 7;          // token within pair
        int quad = t & 127;       // channel quad 0..127
        int hh = quad >> 4;       // head
        int li = quad & 15;       // quad within head
        size_t g = (size_t)(tok0 + tk) * E + (quad << 2);
        float4 vq = *(const float4*)(query + g);
        float4 vk = *(const float4*)(keys + g);
        float4 vv = *(const float4*)(values + g);
        float4 vp = *(const float4*)(pos + g);
        int o = hh * XS + (li << 2);
        *(float4*)&x_lds[0][tk][o] = vq;
        *(float4*)&x_lds[1][tk][o] = vk;
        *(float4*)&x_lds[2][tk][o] = vv;
        *(float4*)&x_lds[3][tk][o] = vp;
    }
    __syncthreads();

    int tk = t >> 7;
    int quad = t & 127;
    int h = quad >> 4;
    int li = quad & 15;
    const float* xq = &x_lds[0][tk][h * XS];
    const float* xk = &x_lds[1][tk][h * XS];
    const float* xv = &x_lds[2][tk][h * XS];
    const float* xp = &x_lds[3][tk][h * XS];
    const float4* wq4 = (const float4*)WqT + li;
    const float4* wk4 = (const float4*)WkT + li;
    const float4* wv4 = (const float4*)WvT + li;
    const float4* wpq4 = (const float4*)WpqT + li;
    const float4* wpk4 = (const float4*)WpkT + li;

    float4 aq = {0, 0, 0, 0}, ak = {0, 0, 0, 0}, av = {0, 0, 0, 0};
    float4 apq = {0, 0, 0, 0}, apk = {0, 0, 0, 0};
#pragma unroll 8
    for (int j = 0; j < 64; j++) {
        float xqj = xq[j], xkj = xk[j], xvj = xv[j], xpj = xp[j];
        float4 w;
        w = wq4[j << 4];
        aq.x = fmaf(xqj, w.x, aq.x); aq.y = fmaf(xqj, w.y, aq.y);
        aq.z = fmaf(xqj, w.z, aq.z); aq.w = fmaf(xqj, w.w, aq.w);
        w = wk4[j << 4];
        ak.x = fmaf(xkj, w.x, ak.x); ak.y = fmaf(xkj, w.y, ak.y);
        ak.z = fmaf(xkj, w.z, ak.z); ak.w = fmaf(xkj, w.w, ak.w);
        w = wv4[j << 4];
        av.x = fmaf(xvj, w.x, av.x); av.y = fmaf(xvj, w.y, av.y);
        av.z = fmaf(xvj, w.z, av.z); av.w = fmaf(xvj, w.w, av.w);
        w = wpq4[j << 4];
        apq.x = fmaf(xpj, w.x, apq.x); apq.y = fmaf(xpj, w.y, apq.y);
        apq.z = fmaf(xpj, w.z, apq.z); apq.w = fmaf(xpj, w.w, apq.w);
        w = wpk4[j << 4];
        apk.x = fmaf(xpj, w.x, apk.x); apk.y = fmaf(xpj, w.y, apk.y);
        apk.z = fmaf(xpj, w.z, apk.z); apk.w = fmaf(xpj, w.w, apk.w);
    }
    {
        size_t g = (size_t)(tok0 + tk) * E + (h << 6) + (li << 2);
        *(float4*)(qv_ws + g) = aq;
        *(float4*)(kv_ws + g) = ak;
        *(float4*)(vv_ws + g) = av;
        *(float4*)(pq_ws + g) = apq;
        *(float4*)(pk_ws + g) = apk;
        int o = h * XS + (li << 2);
        *(float4*)&qk_lds[0][tk][o] = aq;
        *(float4*)&qk_lds[1][tk][o] = ak;
    }
    __syncthreads();

    // ---- phase 2: qrk = q @ Wrk (row-major Wrk[i][d], coalesced float4 in d)
    {
        const float* qh = &qk_lds[0][tk][h * XS];
        const float* kh = &qk_lds[1][tk][h * XS];
        const float4* wrk4 = (const float4*)Wrk + li;
        const float4* wrq4 = (const float4*)Wrq + li;
        float4 ark = {0, 0, 0, 0}, arq = {0, 0, 0, 0};
#pragma unroll 8
        for (int i = 0; i < 64; i++) {
            float qi = qh[i], ki = kh[i];
            float4 w;
            w = wrk4[i << 4];
            ark.x = fmaf(qi, w.x, ark.x); ark.y = fmaf(qi, w.y, ark.y);
            ark.z = fmaf(qi, w.z, ark.z); ark.w = fmaf(qi, w.w, ark.w);
            w = wrq4[i << 4];
            arq.x = fmaf(ki, w.x, arq.x); arq.y = fmaf(ki, w.y, arq.y);
            arq.z = fmaf(ki, w.z, arq.z); arq.w = fmaf(ki, w.w, arq.w);
        }
        size_t g = (size_t)(tok0 + tk) * E + (h << 6) + (li << 2);
        *(float4*)(qrk_ws + g) = ark;
        *(float4*)(krq_ws + g) = arq;
    }
}

// ---------------- K2pre: e_ws = (q.k + pq.pk)*rsqrt2 + mask ----------------
__global__ __launch_bounds__(256) void k2pre(
    const float* __restrict__ qv_ws, const float* __restrict__ kv_ws,
    const float* __restrict__ pq_ws, const float* __restrict__ pk_ws,
    const float* __restrict__ mask, float* __restrict__ e_ws) {
    __shared__ float qs[8 * 64], ps[8 * 64];
    int t = threadIdx.x;
    int b = blockIdx.x;
    int qt = b & 31;
    int h = (b >> 5) & 7;
    int n = b >> 8;
    int nb = n << 8;
    int q0 = qt << 3;
    int k = t;
#pragma unroll
    for (int it = 0; it < 2; it++) {
        int idx = t + (it << 8);
        int q = idx >> 6, d = idx & 63;
        size_t g = (size_t)(nb + q0 + q) * E + (h << 6) + d;
        qs[idx] = qv_ws[g];
        ps[idx] = pq_ws[g];
    }
    __syncthreads();
    const float4* kv4p = (const float4*)(kv_ws + (size_t)(nb + k) * E + (h << 6));
    const float4* pk4p = (const float4*)(pk_ws + (size_t)(nb + k) * E + (h << 6));
    float acc[8];
#pragma unroll
    for (int q = 0; q < 8; q++) acc[q] = 0.f;
#pragma unroll
    for (int d4 = 0; d4 < 16; d4++) {
        float4 kv4 = kv4p[d4];
        float4 pk4 = pk4p[d4];
#pragma unroll
        for (int q = 0; q < 8; q++) {
            float4 q4 = ((const float4*)qs)[(q << 4) + d4];
            float4 p4 = ((const float4*)ps)[(q << 4) + d4];
            float a = acc[q];
            a = fmaf(q4.x, kv4.x, a);
            a = fmaf(q4.y, kv4.y, a);
            a = fmaf(q4.z, kv4.z, a);
            a = fmaf(q4.w, kv4.w, a);
            a = fmaf(p4.x, pk4.x, a);
            a = fmaf(p4.y, pk4.y, a);
            a = fmaf(p4.z, pk4.z, a);
            a = fmaf(p4.w, pk4.w, a);
            acc[q] = a;
        }
    }
    float mk = (1.0f - mask[nb + k]) * (-1e9f);
#pragma unroll
    for (int q = 0; q < 8; q++) {
        e_ws[(size_t)(nb + q0 + q) * (H * L) + (h << 8) + k] = acc[q] * RSQRT2 + mk;
    }
}

// ---------------- K2f: fused rel-energy + softmax + attn@V ----------------
#define K2F_LOAD(RR, RK, b_)                                              \
    do {                                                                  \
        _Pragma("unroll") for (int jj = 0; jj < 8; jj++) {                \
            int k_ = ((b_) << 4) + (jj << 1) + rowsel;                    \
            RR[jj] = *(const float4*)(relb + ((size_t)k_ << 9) + cq);     \
            RK[jj] = *(const float4*)(krqb + ((size_t)k_ << 9) + cq);     \
        }                                                                 \
    } while (0)

#define K2F_COMP(RR, RK, b_)                                              \
    do {                                                                  \
        _Pragma("unroll") for (int jj = 0; jj < 8; jj++) {                \
            float wx = qrk4.x + RK[jj].x;                                 \
            float wy = qrk4.y + RK[jj].y;                                 \
            float wz = qrk4.z + RK[jj].z;                                 \
            float ww = qrk4.w + RK[jj].w;                                 \
            float p = RR[jj].x * wx;                                      \
            p = fmaf(RR[jj].y, wy, p);                                    \
            p = fmaf(RR[jj].z, wz, p);                                    \
            p = fmaf(RR[jj].w, ww, p);                                    \
            p += __shfl_down(p, 8, 16);                                   \
            p += __shfl_down(p, 4, 16);                                   \
            p += __shfl_down(p, 2, 16);                                   \
            p += __shfl_down(p, 1, 16);                                   \
            if (sub == 0) {                                               \
                int k_ = ((b_) << 4) + (jj << 1) + rowsel;                \
                r_s[(h << 8) + k_] = p * RSQRT2;                          \
            }                                                             \
        }                                                                 \
    } while (0)

__global__ __launch_bounds__(256, 2) void k2f(
    const float* __restrict__ rel, const float* __restrict__ qrk_ws,
    const float* __restrict__ krq_ws, const float* __restrict__ e_ws,
    const float* __restrict__ vv_ws, float* __restrict__ attn_ws) {
    __shared__ float e_s[H * L];
    __shared__ float r_s[H * L];
    __shared__ float PS[2 * E];
    __shared__ float inv_s[H];
    int t = threadIdx.x;
    int nq = blockIdx.x;
    int n = nq >> 8;

    {
        const float4* src = (const float4*)(e_ws + (size_t)nq * (H * L));
        ((float4*)e_s)[t] = src[t];
        ((float4*)e_s)[t + 256] = src[t + 256];
    }

    int lane128 = t & 127;
    int rowsel = t >> 7;
    int cq = lane128 << 2;
    int h = lane128 >> 4;
    int sub = t & 15;

    const float* relb = rel + (((size_t)nq) << 8) * E;
    const float* krqb = krq_ws + (((size_t)(n << 8))) * E;
    float4 qrk4 = *(const float4*)(qrk_ws + (size_t)nq * E + cq);

    float4 rAr[8], rAk[8], rBr[8], rBk[8];
    K2F_LOAD(rAr, rAk, 0);
#pragma unroll
    for (int b = 0; b < 16; b += 2) {
        K2F_LOAD(rBr, rBk, b + 1);
        K2F_COMP(rAr, rAk, b);
        if (b + 2 < 16) K2F_LOAD(rAr, rAk, b + 2);
        K2F_COMP(rBr, rBk, b + 1);
    }
    __syncthreads();

    {
        int hh = t >> 5;
        int l32 = t & 31;
        float* eh = e_s + (hh << 8);
        const float* rh = r_s + (hh << 8);
        float x[8];
        float m = -INFINITY;
#pragma unroll
        for (int j = 0; j < 8; j++) {
            int idx = l32 + (j << 5);
            x[j] = eh[idx] + rh[idx];
            m = fmaxf(m, x[j]);
        }
#pragma unroll
        for (int off = 16; off > 0; off >>= 1) m = fmaxf(m, __shfl_xor(m, off, 32));
        float s = 0.f;
#pragma unroll
        for (int j = 0; j < 8; j++) {
            int idx = l32 + (j << 5);
            float ev = __expf(x[j] - m);
            eh[idx] = ev;
            s += ev;
        }
#pragma unroll
        for (int off = 16; off > 0; off >>= 1) s += __shfl_xor(s, off, 32);
        if (l32 == 0) inv_s[hh] = 1.0f / s;
    }
    __syncthreads();

    {
        int c4 = (t & 127) << 2;
        int kseg = t >> 7;
        int h1 = c4 >> 6;
        const float* eh = e_s + (h1 << 8) + (kseg << 7);
        const float* vb = vv_ws + ((size_t)((n << 8) + (kseg << 7))) * E + c4;
        float4 acc = {0.f, 0.f, 0.f, 0.f};
#pragma unroll 16
        for (int k = 0; k < 128; k++) {
            float ev = eh[k];
            float4 v4 = *(const float4*)(vb + ((size_t)k << 9));
            acc.x = fmaf(ev, v4.x, acc.x);
            acc.y = fmaf(ev, v4.y, acc.y);
            acc.z = fmaf(ev, v4.z, acc.z);
            acc.w = fmaf(ev, v4.w, acc.w);
        }
        *(float4*)(PS + kseg * E + c4) = acc;
    }
    __syncthreads();

    {
        float v0 = PS[t] + PS[E + t];
        attn_ws[(size_t)nq * E + t] = v0 * inv_s[t >> 6];
        float v1 = PS[256 + t] + PS[E + 256 + t];
        attn_ws[(size_t)nq * E + 256 + t] = v1 * inv_s[(256 + t) >> 6];
    }
}

// ---------------- K3: out = attn @ Wout.T + bout (4 rows / block) ----------------
__global__ __launch_bounds__(512) void k3_out(const float* __restrict__ attn_ws,
                                              const float* __restrict__ WoutT,
                                              const float* __restrict__ bout,
                                              float* __restrict__ out) {
    __shared__ float As[4 * E];
    int t = threadIdx.x;
    int r0 = blockIdx.x << 2;
    for (int j = t; j < 4 * E; j += 512) As[j] = attn_ws[(size_t)r0 * E + j];
    __syncthreads();
    float b0 = bout[t];
    float a0 = b0, a1 = b0, a2 = b0, a3 = b0;
#pragma unroll 8
    for (int c = 0; c < E; c++) {
        float w = WoutT[((size_t)c << 9) + t];
        a0 = fmaf(As[c], w, a0);
        a1 = fmaf(As[E + c], w, a1);
        a2 = fmaf(As[2 * E + c], w, a2);
        a3 = fmaf(As[3 * E + c], w, a3);
    }
    out[(size_t)(r0 + 0) * E + t] = a0;
    out[(size_t)(r0 + 1) * E + t] = a1;
    out[(size_t)(r0 + 2) * E + t] = a2;
    out[(size_t)(r0 + 3) * E + t] = a3;
}

extern "C" void kernel_launch(void* const* d_in, const int* in_sizes, int n_in,
                              void* d_out, int out_size, void* d_ws, size_t ws_size,
                              hipStream_t stream) {
    const float* values = (const float*)d_in[0];
    const float* keys = (const float*)d_in[1];
    const float* query = (const float*)d_in[2];
    const float* pos = (const float*)d_in[3];
    const float* rel = (const float*)d_in[4];
    const float* mask = (const float*)d_in[5];
    const float* Wv = (const float*)d_in[6];
    const float* Wk = (const float*)d_in[7];
    const float* Wq = (const float*)d_in[8];
    const float* Wpq = (const float*)d_in[9];
    const float* Wpk = (const float*)d_in[10];
    const float* Wrk = (const float*)d_in[11];
    const float* Wrq = (const float*)d_in[12];
    const float* Wout = (const float*)d_in[13];
    const float* bout = (const float*)d_in[14];
    float* out = (float*)d_out;

    float* ws = (float*)d_ws;
    const size_t SZ = (size_t)NL * E;  // 262144 floats = 1 MB
    float* qv_ws = ws + 0 * SZ;
    float* kv_ws = ws + 1 * SZ;
    float* vv_ws = ws + 2 * SZ;
    float* pq_ws = ws + 3 * SZ;
    float* pk_ws = ws + 4 * SZ;
    float* qrk_ws = ws + 5 * SZ;
    float* krq_ws = ws + 6 * SZ;
    float* attn_ws = ws + 7 * SZ;
    float* WoutT = ws + 8 * SZ;
    float* e_ws = ws + 9 * SZ;                   // NL*H*L floats = 4 MB
    float* WqT = e_ws + (size_t)NL * (H * L);    // 5 x 4096 floats
    float* WkT = WqT + 4096;
    float* WvT = WkT + 4096;
    float* WpqT = WvT + 4096;
    float* WpkT = WpqT + 4096;

    k0_transpose<<<69, 256, 0, stream>>>(Wout, WoutT, Wq, Wk, Wv, Wpq, Wpk,
                                         WqT, WkT, WvT, WpqT, WpkT);
    k1_proj<<<NL / 2, 256, 0, stream>>>(values, keys, query, pos, WqT, WkT,
                                        WvT, WpqT, WpkT, Wrk, Wrq, qv_ws,
                                        kv_ws, vv_ws, pq_ws, pk_ws, qrk_ws,
                                        krq_ws);
    k2pre<<<512, 256, 0, stream>>>(qv_ws, kv_ws, pq_ws, pk_ws, mask, e_ws);
    k2f<<<512, 256, 0, stream>>>(rel, qrk_ws, krq_ws, e_ws, vv_ws, attn_ws);
    k3_out<<<NL / 4, 512, 0, stream>>>(attn_ws, WoutT, bout, out);
}

// Round 9
// 529.223 us; speedup vs baseline: 3.0772x; 1.0080x over previous
//
#include <hip/hip_runtime.h>
#include <hip/hip_bf16.h>

#define NB 2
#define L 256
#define H 8
#define D 64
#define E 512
#define NL (NB * L)
#define RSQRT2 0.70710678118654752f

// ---------------- K0: transpose Wout [E][E] -> WoutT [c][e], plus the five
// 64x64 head weights (Wq,Wk,Wv,Wpq,Wpk) -> WT[j][i] copies for k1's
// coalesced reads. Grid = 64 Wout tiles + 5 small matrices.
__global__ __launch_bounds__(256) void k0_transpose(
    const float* __restrict__ Wout, float* __restrict__ WoutT,
    const float* __restrict__ Wq, const float* __restrict__ Wk,
    const float* __restrict__ Wv, const float* __restrict__ Wpq,
    const float* __restrict__ Wpk,
    float* __restrict__ WqT, float* __restrict__ WkT, float* __restrict__ WvT,
    float* __restrict__ WpqT, float* __restrict__ WpkT) {
    __shared__ float tile[64][65];
    int t = threadIdx.x;
    int tx = t & 63, ty = t >> 6;  // ty 0..3
    if (blockIdx.x < 64) {
        int bi = blockIdx.x >> 3;   // e-tile
        int bj = blockIdx.x & 7;    // c-tile
#pragma unroll
        for (int m = 0; m < 16; m++) {
            int el = ty + (m << 2);
            tile[el][tx] = Wout[(size_t)(bi * 64 + el) * E + bj * 64 + tx];
        }
        __syncthreads();
#pragma unroll
        for (int m = 0; m < 16; m++) {
            int cl = ty + (m << 2);
            WoutT[(size_t)(bj * 64 + cl) * E + bi * 64 + tx] = tile[tx][cl];
        }
    } else {
        const float* src;
        float* dst;
        switch (blockIdx.x - 64) {
            case 0: src = Wq;  dst = WqT;  break;
            case 1: src = Wk;  dst = WkT;  break;
            case 2: src = Wv;  dst = WvT;  break;
            case 3: src = Wpq; dst = WpqT; break;
            default: src = Wpk; dst = WpkT; break;
        }
#pragma unroll
        for (int m = 0; m < 16; m++) {
            int r = ty + (m << 2);
            tile[r][tx] = src[(r << 6) + tx];
        }
        __syncthreads();
#pragma unroll
        for (int m = 0; m < 16; m++) {
            int r = ty + (m << 2);
            dst[(r << 6) + tx] = tile[tx][r];  // WT[r][c] = W[c][r]
        }
    }
}

// ---------------- K1 v5: one token/block, 512 blocks (2/CU, 8 waves/CU).
// Thread t: head h = t>>5, li = t&31, owns channels h*64 + {2li, 2li+1}.
// Weight reads: (float2*)WT + li + j*32 -> 32 lanes = 256B contiguous,
// upper 32 lanes broadcast. x via bank-padded LDS (stride 66, 2-way max).
#define XP 66  // padded per-head row stride in floats

__global__ __launch_bounds__(256) void k1_proj(
    const float* __restrict__ values, const float* __restrict__ keys,
    const float* __restrict__ query, const float* __restrict__ pos,
    const float* __restrict__ WqT, const float* __restrict__ WkT,
    const float* __restrict__ WvT, const float* __restrict__ WpqT,
    const float* __restrict__ WpkT, const float* __restrict__ Wrk,
    const float* __restrict__ Wrq,
    float* __restrict__ qv_ws, float* __restrict__ kv_ws,
    float* __restrict__ vv_ws, float* __restrict__ pq_ws,
    float* __restrict__ pk_ws, float* __restrict__ qrk_ws,
    float* __restrict__ krq_ws) {
    __shared__ float x_lds[4][8 * XP];   // [array][head*XP + j]
    __shared__ float qk_lds[2][8 * XP];  // [q/k][head*XP + i]
    int t = threadIdx.x;
    int tok = blockIdx.x;
    size_t base = (size_t)tok * E;

    // stage inputs: thread t loads float4 #t&127 of each array (128 quads)
    {
        int quad = t & 127;
        int hh = quad >> 4, li4 = quad & 15;
        int o = hh * XP + (li4 << 2);
        size_t g = base + (quad << 2);
        if (t < 128) {
            *(float4*)&x_lds[0][o] = *(const float4*)(query + g);
            *(float4*)&x_lds[1][o] = *(const float4*)(keys + g);
        } else {
            *(float4*)&x_lds[2][o] = *(const float4*)(values + g);
            *(float4*)&x_lds[3][o] = *(const float4*)(pos + g);
        }
    }
    __syncthreads();

    int h = t >> 5;
    int li = t & 31;
    const float* xq = &x_lds[0][h * XP];
    const float* xk = &x_lds[1][h * XP];
    const float* xv = &x_lds[2][h * XP];
    const float* xp = &x_lds[3][h * XP];
    const float2* wq2 = (const float2*)WqT + li;
    const float2* wk2 = (const float2*)WkT + li;
    const float2* wv2 = (const float2*)WvT + li;
    const float2* wpq2 = (const float2*)WpqT + li;
    const float2* wpk2 = (const float2*)WpkT + li;

    float2 aq = {0, 0}, ak = {0, 0}, av = {0, 0}, apq = {0, 0}, apk = {0, 0};
#pragma unroll 8
    for (int j = 0; j < 64; j++) {
        float xqj = xq[j], xkj = xk[j], xvj = xv[j], xpj = xp[j];
        float2 w;
        w = wq2[j << 5];
        aq.x = fmaf(xqj, w.x, aq.x); aq.y = fmaf(xqj, w.y, aq.y);
        w = wk2[j << 5];
        ak.x = fmaf(xkj, w.x, ak.x); ak.y = fmaf(xkj, w.y, ak.y);
        w = wv2[j << 5];
        av.x = fmaf(xvj, w.x, av.x); av.y = fmaf(xvj, w.y, av.y);
        w = wpq2[j << 5];
        apq.x = fmaf(xpj, w.x, apq.x); apq.y = fmaf(xpj, w.y, apq.y);
        w = wpk2[j << 5];
        apk.x = fmaf(xpj, w.x, apk.x); apk.y = fmaf(xpj, w.y, apk.y);
    }
    {
        size_t g = base + (h << 6) + (li << 1);
        *(float2*)(qv_ws + g) = aq;
        *(float2*)(kv_ws + g) = ak;
        *(float2*)(vv_ws + g) = av;
        *(float2*)(pq_ws + g) = apq;
        *(float2*)(pk_ws + g) = apk;
        int o = h * XP + (li << 1);
        *(float2*)&qk_lds[0][o] = aq;
        *(float2*)&qk_lds[1][o] = ak;
    }
    __syncthreads();

    // phase 2: qrk = q @ Wrk, krq = k @ Wrq (row-major [i][d], coalesced)
    {
        const float* qh = &qk_lds[0][h * XP];
        const float* kh = &qk_lds[1][h * XP];
        const float2* wrk2 = (const float2*)Wrk + li;
        const float2* wrq2 = (const float2*)Wrq + li;
        float2 ark = {0, 0}, arq = {0, 0};
#pragma unroll 8
        for (int i = 0; i < 64; i++) {
            float qi = qh[i], ki = kh[i];
            float2 w;
            w = wrk2[i << 5];
            ark.x = fmaf(qi, w.x, ark.x); ark.y = fmaf(qi, w.y, ark.y);
            w = wrq2[i << 5];
            arq.x = fmaf(ki, w.x, arq.x); arq.y = fmaf(ki, w.y, arq.y);
        }
        size_t g = base + (h << 6) + (li << 1);
        *(float2*)(qrk_ws + g) = ark;
        *(float2*)(krq_ws + g) = arq;
    }
}

// ---------------- K2pre: e_ws = (q.k + pq.pk)*rsqrt2 + mask ----------------
__global__ __launch_bounds__(256) void k2pre(
    const float* __restrict__ qv_ws, const float* __restrict__ kv_ws,
    const float* __restrict__ pq_ws, const float* __restrict__ pk_ws,
    const float* __restrict__ mask, float* __restrict__ e_ws) {
    __shared__ float qs[8 * 64], ps[8 * 64];
    int t = threadIdx.x;
    int b = blockIdx.x;
    int qt = b & 31;
    int h = (b >> 5) & 7;
    int n = b >> 8;
    int nb = n << 8;
    int q0 = qt << 3;
    int k = t;
#pragma unroll
    for (int it = 0; it < 2; it++) {
        int idx = t + (it << 8);
        int q = idx >> 6, d = idx & 63;
        size_t g = (size_t)(nb + q0 + q) * E + (h << 6) + d;
        qs[idx] = qv_ws[g];
        ps[idx] = pq_ws[g];
    }
    __syncthreads();
    const float4* kv4p = (const float4*)(kv_ws + (size_t)(nb + k) * E + (h << 6));
    const float4* pk4p = (const float4*)(pk_ws + (size_t)(nb + k) * E + (h << 6));
    float acc[8];
#pragma unroll
    for (int q = 0; q < 8; q++) acc[q] = 0.f;
#pragma unroll
    for (int d4 = 0; d4 < 16; d4++) {
        float4 kv4 = kv4p[d4];
        float4 pk4 = pk4p[d4];
#pragma unroll
        for (int q = 0; q < 8; q++) {
            float4 q4 = ((const float4*)qs)[(q << 4) + d4];
            float4 p4 = ((const float4*)ps)[(q << 4) + d4];
            float a = acc[q];
            a = fmaf(q4.x, kv4.x, a);
            a = fmaf(q4.y, kv4.y, a);
            a = fmaf(q4.z, kv4.z, a);
            a = fmaf(q4.w, kv4.w, a);
            a = fmaf(p4.x, pk4.x, a);
            a = fmaf(p4.y, pk4.y, a);
            a = fmaf(p4.z, pk4.z, a);
            a = fmaf(p4.w, pk4.w, a);
            acc[q] = a;
        }
    }
    float mk = (1.0f - mask[nb + k]) * (-1e9f);
#pragma unroll
    for (int q = 0; q < 8; q++) {
        e_ws[(size_t)(nb + q0 + q) * (H * L) + (h << 8) + k] = acc[q] * RSQRT2 + mk;
    }
}

// ---------------- K2f: fused rel-energy + softmax + attn@V ----------------
#define K2F_LOAD(RR, RK, b_)                                              \
    do {                                                                  \
        _Pragma("unroll") for (int jj = 0; jj < 8; jj++) {                \
            int k_ = ((b_) << 4) + (jj << 1) + rowsel;                    \
            RR[jj] = *(const float4*)(relb + ((size_t)k_ << 9) + cq);     \
            RK[jj] = *(const float4*)(krqb + ((size_t)k_ << 9) + cq);     \
        }                                                                 \
    } while (0)

#define K2F_COMP(RR, RK, b_)                                              \
    do {                                                                  \
        _Pragma("unroll") for (int jj = 0; jj < 8; jj++) {                \
            float wx = qrk4.x + RK[jj].x;                                 \
            float wy = qrk4.y + RK[jj].y;                                 \
            float wz = qrk4.z + RK[jj].z;                                 \
            float ww = qrk4.w + RK[jj].w;                                 \
            float p = RR[jj].x * wx;                                      \
            p = fmaf(RR[jj].y, wy, p);                                    \
            p = fmaf(RR[jj].z, wz, p);                                    \
            p = fmaf(RR[jj].w, ww, p);                                    \
            p += __shfl_down(p, 8, 16);                                   \
            p += __shfl_down(p, 4, 16);                                   \
            p += __shfl_down(p, 2, 16);                                   \
            p += __shfl_down(p, 1, 16);                                   \
            if (sub == 0) {                                               \
                int k_ = ((b_) << 4) + (jj << 1) + rowsel;                \
                r_s[(h << 8) + k_] = p * RSQRT2;                          \
            }                                                             \
        }                                                                 \
    } while (0)

__global__ __launch_bounds__(256, 2) void k2f(
    const float* __restrict__ rel, const float* __restrict__ qrk_ws,
    const float* __restrict__ krq_ws, const float* __restrict__ e_ws,
    const float* __restrict__ vv_ws, float* __restrict__ attn_ws) {
    __shared__ float e_s[H * L];
    __shared__ float r_s[H * L];
    __shared__ float PS[2 * E];
    __shared__ float inv_s[H];
    int t = threadIdx.x;
    int nq = blockIdx.x;
    int n = nq >> 8;

    {
        const float4* src = (const float4*)(e_ws + (size_t)nq * (H * L));
        ((float4*)e_s)[t] = src[t];
        ((float4*)e_s)[t + 256] = src[t + 256];
    }

    int lane128 = t & 127;
    int rowsel = t >> 7;
    int cq = lane128 << 2;
    int h = lane128 >> 4;
    int sub = t & 15;

    const float* relb = rel + (((size_t)nq) << 8) * E;
    const float* krqb = krq_ws + (((size_t)(n << 8))) * E;
    float4 qrk4 = *(const float4*)(qrk_ws + (size_t)nq * E + cq);

    float4 rAr[8], rAk[8], rBr[8], rBk[8];
    K2F_LOAD(rAr, rAk, 0);
#pragma unroll
    for (int b = 0; b < 16; b += 2) {
        K2F_LOAD(rBr, rBk, b + 1);
        K2F_COMP(rAr, rAk, b);
        if (b + 2 < 16) K2F_LOAD(rAr, rAk, b + 2);
        K2F_COMP(rBr, rBk, b + 1);
    }
    __syncthreads();

    {
        int hh = t >> 5;
        int l32 = t & 31;
        float* eh = e_s + (hh << 8);
        const float* rh = r_s + (hh << 8);
        float x[8];
        float m = -INFINITY;
#pragma unroll
        for (int j = 0; j < 8; j++) {
            int idx = l32 + (j << 5);
            x[j] = eh[idx] + rh[idx];
            m = fmaxf(m, x[j]);
        }
#pragma unroll
        for (int off = 16; off > 0; off >>= 1) m = fmaxf(m, __shfl_xor(m, off, 32));
        float s = 0.f;
#pragma unroll
        for (int j = 0; j < 8; j++) {
            int idx = l32 + (j << 5);
            float ev = __expf(x[j] - m);
            eh[idx] = ev;
            s += ev;
        }
#pragma unroll
        for (int off = 16; off > 0; off >>= 1) s += __shfl_xor(s, off, 32);
        if (l32 == 0) inv_s[hh] = 1.0f / s;
    }
    __syncthreads();

    {
        int c4 = (t & 127) << 2;
        int kseg = t >> 7;
        int h1 = c4 >> 6;
        const float* eh = e_s + (h1 << 8) + (kseg << 7);
        const float* vb = vv_ws + ((size_t)((n << 8) + (kseg << 7))) * E + c4;
        float4 acc = {0.f, 0.f, 0.f, 0.f};
#pragma unroll 16
        for (int k = 0; k < 128; k++) {
            float ev = eh[k];
            float4 v4 = *(const float4*)(vb + ((size_t)k << 9));
            acc.x = fmaf(ev, v4.x, acc.x);
            acc.y = fmaf(ev, v4.y, acc.y);
            acc.z = fmaf(ev, v4.z, acc.z);
            acc.w = fmaf(ev, v4.w, acc.w);
        }
        *(float4*)(PS + kseg * E + c4) = acc;
    }
    __syncthreads();

    {
        float v0 = PS[t] + PS[E + t];
        attn_ws[(size_t)nq * E + t] = v0 * inv_s[t >> 6];
        float v1 = PS[256 + t] + PS[E + 256 + t];
        attn_ws[(size_t)nq * E + 256 + t] = v1 * inv_s[(256 + t) >> 6];
    }
}

// ---------------- K3: out = attn @ Wout.T + bout (4 rows / block) ----------------
__global__ __launch_bounds__(512) void k3_out(const float* __restrict__ attn_ws,
                                              const float* __restrict__ WoutT,
                                              const float* __restrict__ bout,
                                              float* __restrict__ out) {
    __shared__ float As[4 * E];
    int t = threadIdx.x;
    int r0 = blockIdx.x << 2;
    for (int j = t; j < 4 * E; j += 512) As[j] = attn_ws[(size_t)r0 * E + j];
    __syncthreads();
    float b0 = bout[t];
    float a0 = b0, a1 = b0, a2 = b0, a3 = b0;
#pragma unroll 8
    for (int c = 0; c < E; c++) {
        float w = WoutT[((size_t)c << 9) + t];
        a0 = fmaf(As[c], w, a0);
        a1 = fmaf(As[E + c], w, a1);
        a2 = fmaf(As[2 * E + c], w, a2);
        a3 = fmaf(As[3 * E + c], w, a3);
    }
    out[(size_t)(r0 + 0) * E + t] = a0;
    out[(size_t)(r0 + 1) * E + t] = a1;
    out[(size_t)(r0 + 2) * E + t] = a2;
    out[(size_t)(r0 + 3) * E + t] = a3;
}

extern "C" void kernel_launch(void* const* d_in, const int* in_sizes, int n_in,
                              void* d_out, int out_size, void* d_ws, size_t ws_size,
                              hipStream_t stream) {
    const float* values = (const float*)d_in[0];
    const float* keys = (const float*)d_in[1];
    const float* query = (const float*)d_in[2];
    const float* pos = (const float*)d_in[3];
    const float* rel = (const float*)d_in[4];
    const float* mask = (const float*)d_in[5];
    const float* Wv = (const float*)d_in[6];
    const float* Wk = (const float*)d_in[7];
    const float* Wq = (const float*)d_in[8];
    const float* Wpq = (const float*)d_in[9];
    const float* Wpk = (const float*)d_in[10];
    const float* Wrk = (const float*)d_in[11];
    const float* Wrq = (const float*)d_in[12];
    const float* Wout = (const float*)d_in[13];
    const float* bout = (const float*)d_in[14];
    float* out = (float*)d_out;

    float* ws = (float*)d_ws;
    const size_t SZ = (size_t)NL * E;  // 262144 floats = 1 MB
    float* qv_ws = ws + 0 * SZ;
    float* kv_ws = ws + 1 * SZ;
    float* vv_ws = ws + 2 * SZ;
    float* pq_ws = ws + 3 * SZ;
    float* pk_ws = ws + 4 * SZ;
    float* qrk_ws = ws + 5 * SZ;
    float* krq_ws = ws + 6 * SZ;
    float* attn_ws = ws + 7 * SZ;
    float* WoutT = ws + 8 * SZ;
    float* e_ws = ws + 9 * SZ;                   // NL*H*L floats = 4 MB
    float* WqT = e_ws + (size_t)NL * (H * L);    // 5 x 4096 floats
    float* WkT = WqT + 4096;
    float* WvT = WkT + 4096;
    float* WpqT = WvT + 4096;
    float* WpkT = WpqT + 4096;

    k0_transpose<<<69, 256, 0, stream>>>(Wout, WoutT, Wq, Wk, Wv, Wpq, Wpk,
                                         WqT, WkT, WvT, WpqT, WpkT);
    k1_proj<<<NL, 256, 0, stream>>>(values, keys, query, pos, WqT, WkT, WvT,
                                    WpqT, WpkT, Wrk, Wrq, qv_ws, kv_ws, vv_ws,
                                    pq_ws, pk_ws, qrk_ws, krq_ws);
    k2pre<<<512, 256, 0, stream>>>(qv_ws, kv_ws, pq_ws, pk_ws, mask, e_ws);
    k2f<<<512, 256, 0, stream>>>(rel, qrk_ws, krq_ws, e_ws, vv_ws, attn_ws);
    k3_out<<<NL / 4, 512, 0, stream>>>(attn_ws, WoutT, bout, out);
}